// Round 3
// baseline (1421.949 us; speedup 1.0000x reference)
//
#include <hip/hip_runtime.h>
#include <hip/hip_bf16.h>
#include <stdint.h>

// Problem constants (from reference)
#define N_SAM 10000
#define N_GEN 20000
#define DSAM  2000
#define DGEN  500
#define DIM0  256

typedef __hip_bfloat16 bf16;

typedef float fvec4 __attribute__((ext_vector_type(4)));
typedef float fvec2 __attribute__((ext_vector_type(2)));

// ---------------------------------------------------------------------------
// Degree histograms (4 at once)
// ---------------------------------------------------------------------------
__global__ __launch_bounds__(256) void hist4_kernel(
    const int* __restrict__ ssg, const int* __restrict__ dsg,
    const int* __restrict__ sgs, const int* __restrict__ dgs,
    unsigned* __restrict__ c_ssg, unsigned* __restrict__ c_dsg,
    unsigned* __restrict__ c_sgs, unsigned* __restrict__ c_dgs, int ne) {
    int i = blockIdx.x * blockDim.x + threadIdx.x;
    if (i < ne) {
        atomicAdd(&c_ssg[ssg[i]], 1u);
        atomicAdd(&c_dsg[dsg[i]], 1u);
        atomicAdd(&c_sgs[sgs[i]], 1u);
        atomicAdd(&c_dgs[dgs[i]], 1u);
    }
}

// ---------------------------------------------------------------------------
// Exclusive scan (single block, chunked Hillis-Steele). row[n] = total.
// Also copies row_ptr into cur (scatter cursors).
// ---------------------------------------------------------------------------
__global__ __launch_bounds__(1024) void scan_kernel(
    const unsigned* __restrict__ cnt, unsigned* __restrict__ row,
    unsigned* __restrict__ cur, int n) {
    __shared__ unsigned sdata[1024];
    __shared__ unsigned carry_s;
    int t = threadIdx.x;
    if (t == 0) carry_s = 0;
    __syncthreads();
    for (int base = 0; base < n; base += 1024) {
        int i = base + t;
        unsigned v = (i < n) ? cnt[i] : 0u;
        sdata[t] = v;
        __syncthreads();
        for (int off = 1; off < 1024; off <<= 1) {
            unsigned add = (t >= off) ? sdata[t - off] : 0u;
            __syncthreads();
            sdata[t] += add;
            __syncthreads();
        }
        unsigned incl = sdata[t];
        unsigned carry = carry_s;
        if (i < n) {
            unsigned ex = carry + incl - v;
            row[i] = ex;
            cur[i] = ex;
        }
        __syncthreads();
        if (t == 1023) carry_s = carry + incl;
        __syncthreads();
    }
    if (t == 0) row[n] = carry_s;
}

// ---------------------------------------------------------------------------
// Degree normalizers: rsqrt(max(deg,1))
// ---------------------------------------------------------------------------
__global__ __launch_bounds__(256) void degnorm_kernel(
    const unsigned* __restrict__ c_ssg, const unsigned* __restrict__ c_dsg,
    const unsigned* __restrict__ c_sgs, const unsigned* __restrict__ c_dgs,
    float* __restrict__ rs_out_sam, float* __restrict__ rs_in_gen,
    float* __restrict__ rs_out_gen, float* __restrict__ rs_in_sam) {
    int i = blockIdx.x * blockDim.x + threadIdx.x;
    if (i < N_SAM) {
        unsigned a = c_ssg[i]; if (a < 1u) a = 1u;
        unsigned b = c_dgs[i]; if (b < 1u) b = 1u;
        rs_out_sam[i] = rsqrtf((float)a);
        rs_in_sam[i]  = rsqrtf((float)b);
    }
    if (i < N_GEN) {
        unsigned a = c_dsg[i]; if (a < 1u) a = 1u;
        unsigned b = c_sgs[i]; if (b < 1u) b = 1u;
        rs_in_gen[i]  = rsqrtf((float)a);
        rs_out_gen[i] = rsqrtf((float)b);
    }
}

// ---------------------------------------------------------------------------
// CSR scatter (dst-sorted edge list; col = src)
// ---------------------------------------------------------------------------
__global__ __launch_bounds__(256) void scatter_kernel(
    const int* __restrict__ src, const int* __restrict__ dst,
    unsigned* __restrict__ cur, int* __restrict__ col, int ne) {
    int i = blockIdx.x * blockDim.x + threadIdx.x;
    if (i < ne) {
        unsigned p = atomicAdd(&cur[dst[i]], 1u);
        col[p] = src[i];
    }
}

// ---------------------------------------------------------------------------
// Tiled GEMM: C[M,N] = rowscale(A)[M,K] * B[K,N] (+ bias), fp32 accumulate.
// A, B: fp32 row-major; C: fp32.
// BM=BN=64, BK=16, 256 threads, 4x4 per thread. Requires N % 64 == 0.
// ---------------------------------------------------------------------------
__global__ __launch_bounds__(256) void gemm_tile(
    const float* __restrict__ A, const float* __restrict__ B,
    const float* __restrict__ rowscale, const float* __restrict__ bias,
    float* __restrict__ C, int M, int N, int K) {
    const int BM = 64, BN = 64, BK = 16;
    __shared__ float As[BK][BM];
    __shared__ float Bs[BK][BN];
    int t  = threadIdx.x;
    int m0 = blockIdx.y * BM, n0 = blockIdx.x * BN;
    int tx = t & 15, ty = t >> 4;
    // loader indices
    int ar = t >> 2;        // A row within tile, 0..63
    int ak = (t & 3) * 4;   // A k offset within tile, {0,4,8,12}
    int bk = t >> 4;        // B k row within tile, 0..15
    int bn = (t & 15) * 4;  // B col offset within tile

    float acc[4][4] = {};

    for (int k0 = 0; k0 < K; k0 += BK) {
        // ---- load A tile (transposed into As[k][m]), fused row scale ----
        int gm = m0 + ar;
        float scale = 1.0f;
        if (rowscale != nullptr && gm < M) scale = rowscale[gm];
        int gk0 = k0 + ak;
        if (gm < M && gk0 + 3 < K) {
            float4 u = *reinterpret_cast<const float4*>(A + (size_t)gm * K + gk0);
            As[ak + 0][ar] = u.x * scale;
            As[ak + 1][ar] = u.y * scale;
            As[ak + 2][ar] = u.z * scale;
            As[ak + 3][ar] = u.w * scale;
        } else {
            #pragma unroll
            for (int j = 0; j < 4; j++) {
                int gk = gk0 + j;
                float v = 0.f;
                if (gm < M && gk < K) v = A[(size_t)gm * K + gk];
                As[ak + j][ar] = v * scale;
            }
        }
        // ---- load B tile ----
        {
            int gk = k0 + bk;
            if (gk < K) {
                float4 u = *reinterpret_cast<const float4*>(B + (size_t)gk * N + n0 + bn);
                Bs[bk][bn + 0] = u.x;
                Bs[bk][bn + 1] = u.y;
                Bs[bk][bn + 2] = u.z;
                Bs[bk][bn + 3] = u.w;
            } else {
                Bs[bk][bn + 0] = 0.f; Bs[bk][bn + 1] = 0.f;
                Bs[bk][bn + 2] = 0.f; Bs[bk][bn + 3] = 0.f;
            }
        }
        __syncthreads();
        // ---- compute ----
        #pragma unroll
        for (int kk = 0; kk < BK; kk++) {
            float4 a = *reinterpret_cast<const float4*>(&As[kk][ty * 4]);
            float4 b = *reinterpret_cast<const float4*>(&Bs[kk][tx * 4]);
            float av[4] = {a.x, a.y, a.z, a.w};
            float bv[4] = {b.x, b.y, b.z, b.w};
            #pragma unroll
            for (int i = 0; i < 4; i++)
                #pragma unroll
                for (int j = 0; j < 4; j++)
                    acc[i][j] += av[i] * bv[j];
        }
        __syncthreads();
    }
    // ---- epilogue ----
    #pragma unroll
    for (int i = 0; i < 4; i++) {
        int gm = m0 + ty * 4 + i;
        if (gm >= M) continue;
        #pragma unroll
        for (int j = 0; j < 4; j++) {
            int gn = n0 + tx * 4 + j;
            float v = acc[i][j];
            if (bias != nullptr) v += bias[gn];
            C[(size_t)gm * N + gn] = v;
        }
    }
}

// ---------------------------------------------------------------------------
// CSR aggregation: out[r,:] = leaky( rs_in[r] * sum_{e in row r} P[col[e],:] + bias )
// One wave per dst row; lane handles VPL contiguous columns (D = 64*VPL).
// ---------------------------------------------------------------------------
template <int VPL> struct VecT;
template <> struct VecT<4> { using T = fvec4; };
template <> struct VecT<2> { using T = fvec2; };
template <> struct VecT<1> { using T = float; };

template <int VPL>
__global__ __launch_bounds__(256) void agg_csr_kernel(
    const unsigned* __restrict__ rowptr, const int* __restrict__ col,
    const float* __restrict__ P, const float* __restrict__ rs_in,
    const float* __restrict__ bias,
    float* __restrict__ outF, int n_dst) {
    const int D = VPL * 64;
    using T = typename VecT<VPL>::T;
    int wave = threadIdx.x >> 6;
    int lane = threadIdx.x & 63;
    int r = blockIdx.x * 4 + wave;
    if (r >= n_dst) return;

    unsigned e0 = rowptr[r], e1 = rowptr[r + 1];
    T acc{};
    T acc2{};
    unsigned e = e0;
    for (; e + 2 <= e1; e += 2) {
        int s0 = col[e];
        int s1 = col[e + 1];
        T v0 = *reinterpret_cast<const T*>(P + (size_t)s0 * D + lane * VPL);
        T v1 = *reinterpret_cast<const T*>(P + (size_t)s1 * D + lane * VPL);
        acc  += v0;
        acc2 += v1;
    }
    if (e < e1) {
        int s0 = col[e];
        T v0 = *reinterpret_cast<const T*>(P + (size_t)s0 * D + lane * VPL);
        acc += v0;
    }
    acc += acc2;

    float rs = rs_in[r];
    float* ap = reinterpret_cast<float*>(&acc);
    #pragma unroll
    for (int j = 0; j < VPL; j++) {
        int c = lane * VPL + j;
        float v = ap[j] * rs + bias[c];
        v = (v >= 0.f) ? v : 0.25f * v;
        outF[(size_t)r * D + c] = v;
    }
}

// ---------------------------------------------------------------------------
// Launch
// ---------------------------------------------------------------------------
extern "C" void kernel_launch(void* const* d_in, const int* in_sizes, int n_in,
                              void* d_out, int out_size, void* d_ws, size_t ws_size,
                              hipStream_t stream) {
    const float* sam_feat = (const float*)d_in[0];
    const float* gen_feat = (const float*)d_in[1];
    const int* src_sg = (const int*)d_in[2];
    const int* dst_sg = (const int*)d_in[3];
    const int* src_gs = (const int*)d_in[4];
    const int* dst_gs = (const int*)d_in[5];
    const float* l1W = (const float*)d_in[6];
    const float* l1b = (const float*)d_in[7];
    const float* l2W = (const float*)d_in[8];
    const float* l2b = (const float*)d_in[9];
    const float* Wsg[3] = {(const float*)d_in[10], (const float*)d_in[14], (const float*)d_in[18]};
    const float* bsg[3] = {(const float*)d_in[11], (const float*)d_in[15], (const float*)d_in[19]};
    const float* Wgs[3] = {(const float*)d_in[12], (const float*)d_in[16], (const float*)d_in[20]};
    const float* bgs[3] = {(const float*)d_in[13], (const float*)d_in[17], (const float*)d_in[21]};
    const int NE = in_sizes[2];

    // ---- workspace carve (all 256B aligned; total ~70.2 MB) ----
    char* base = (char*)d_ws;
    size_t off = 0;
    auto alloc = [&](size_t bytes) -> char* {
        char* p = base + off;
        off = (off + bytes + 255) & ~(size_t)255;
        return p;
    };
    unsigned* cnt_ssg = (unsigned*)alloc(N_SAM * 4);
    unsigned* cnt_dsg = (unsigned*)alloc(N_GEN * 4);
    unsigned* cnt_sgs = (unsigned*)alloc(N_GEN * 4);
    unsigned* cnt_dgs = (unsigned*)alloc(N_SAM * 4);
    size_t cnt_bytes = off;  // contiguous zero region
    unsigned* row_sg = (unsigned*)alloc((N_GEN + 1) * 4);
    unsigned* row_gs = (unsigned*)alloc((N_SAM + 1) * 4);
    unsigned* cur_sg = (unsigned*)alloc(N_GEN * 4);
    unsigned* cur_gs = (unsigned*)alloc(N_SAM * 4);
    float* rs_out_sam = (float*)alloc(N_SAM * 4);
    float* rs_in_sam  = (float*)alloc(N_SAM * 4);
    float* rs_out_gen = (float*)alloc(N_GEN * 4);
    float* rs_in_gen  = (float*)alloc(N_GEN * 4);
    int* col_sg = (int*)alloc((size_t)NE * 4);
    int* col_gs = (int*)alloc((size_t)NE * 4);
    float* hs = (float*)alloc((size_t)N_SAM * 256 * 4);
    float* hg = (float*)alloc((size_t)N_GEN * 256 * 4);
    float* ps = (float*)alloc((size_t)N_SAM * 256 * 4);
    float* pg = (float*)alloc((size_t)N_GEN * 256 * 4);
    (void)ws_size;

    // ---- graph preprocessing ----
    hipMemsetAsync(base, 0, cnt_bytes, stream);
    int neb = (NE + 255) / 256;
    hist4_kernel<<<neb, 256, 0, stream>>>(src_sg, dst_sg, src_gs, dst_gs,
                                          cnt_ssg, cnt_dsg, cnt_sgs, cnt_dgs, NE);
    scan_kernel<<<1, 1024, 0, stream>>>(cnt_dsg, row_sg, cur_sg, N_GEN);
    scan_kernel<<<1, 1024, 0, stream>>>(cnt_dgs, row_gs, cur_gs, N_SAM);
    degnorm_kernel<<<(N_GEN + 255) / 256, 256, 0, stream>>>(
        cnt_ssg, cnt_dsg, cnt_sgs, cnt_dgs,
        rs_out_sam, rs_in_gen, rs_out_gen, rs_in_sam);
    scatter_kernel<<<neb, 256, 0, stream>>>(src_sg, dst_sg, cur_sg, col_sg, NE);
    scatter_kernel<<<neb, 256, 0, stream>>>(src_gs, dst_gs, cur_gs, col_gs, NE);

    dim3 blk(256);
    const int GY_SAM = (N_SAM + 63) / 64;  // 157
    const int GY_GEN = (N_GEN + 63) / 64;  // 313

    // ---- input projections: hs = sam_feat@l1W + l1b ; hg = gen_feat@l2W + l2b ----
    gemm_tile<<<dim3(DIM0 / 64, GY_SAM), blk, 0, stream>>>(
        sam_feat, l1W, nullptr, l1b, hs, N_SAM, DIM0, DSAM);
    gemm_tile<<<dim3(DIM0 / 64, GY_GEN), blk, 0, stream>>>(
        gen_feat, l2W, nullptr, l2b, hg, N_GEN, DIM0, DGEN);

    // ---- layer 1: 256 -> 256 ----
    gemm_tile<<<dim3(4, GY_SAM), blk, 0, stream>>>(hs, Wsg[0], rs_out_sam, nullptr, ps, N_SAM, 256, 256);
    gemm_tile<<<dim3(4, GY_GEN), blk, 0, stream>>>(hg, Wgs[0], rs_out_gen, nullptr, pg, N_GEN, 256, 256);
    agg_csr_kernel<4><<<(N_GEN + 3) / 4, blk, 0, stream>>>(
        row_sg, col_sg, ps, rs_in_gen, bsg[0], hg, N_GEN);
    agg_csr_kernel<4><<<(N_SAM + 3) / 4, blk, 0, stream>>>(
        row_gs, col_gs, pg, rs_in_sam, bgs[0], hs, N_SAM);

    // ---- layer 2: 256 -> 128 ----
    gemm_tile<<<dim3(2, GY_SAM), blk, 0, stream>>>(hs, Wsg[1], rs_out_sam, nullptr, ps, N_SAM, 128, 256);
    gemm_tile<<<dim3(2, GY_GEN), blk, 0, stream>>>(hg, Wgs[1], rs_out_gen, nullptr, pg, N_GEN, 128, 256);
    agg_csr_kernel<2><<<(N_GEN + 3) / 4, blk, 0, stream>>>(
        row_sg, col_sg, ps, rs_in_gen, bsg[1], hg, N_GEN);
    agg_csr_kernel<2><<<(N_SAM + 3) / 4, blk, 0, stream>>>(
        row_gs, col_gs, pg, rs_in_sam, bgs[1], hs, N_SAM);

    // ---- layer 3: 128 -> 64, fp32 outputs straight into d_out ----
    gemm_tile<<<dim3(1, GY_SAM), blk, 0, stream>>>(hs, Wsg[2], rs_out_sam, nullptr, ps, N_SAM, 64, 128);
    gemm_tile<<<dim3(1, GY_GEN), blk, 0, stream>>>(hg, Wgs[2], rs_out_gen, nullptr, pg, N_GEN, 64, 128);
    float* out_sam = (float*)d_out;
    float* out_gen = out_sam + (size_t)N_SAM * 64;
    agg_csr_kernel<1><<<(N_GEN + 3) / 4, blk, 0, stream>>>(
        row_sg, col_sg, ps, rs_in_gen, bsg[2], out_gen, N_GEN);
    agg_csr_kernel<1><<<(N_SAM + 3) / 4, blk, 0, stream>>>(
        row_gs, col_gs, pg, rs_in_sam, bgs[2], out_sam, N_SAM);
}